// Round 8
// baseline (29.448 us; speedup 1.0000x reference)
//
#include <hip/hip_runtime.h>
#include <math.h>

// ModularQTS: B=256, F=64, NT=8, NQ=6 (DQ=64), NA=3 (DA=8), DEG=4, NROTS=24, KLOC=2.
// NEW decomposition: ONE WAVE per batch element (64-thread blocks, grid=256).
// lane = a*8 + qh  (a = ancilla = lane bits 3..5, qh = q bits 3..5 = lane bits 0..2)
// Each lane holds 8 complex amplitudes psi[q = qh*8 + ql, a] over ql = q bits 0..2.
//   q-bit 0..2 gates: register permutes (no cross-lane at all)
//   q-bit 3..5 gates: DPP xor1/xor2/xor4 within the 8-lane qh group
//   ancilla ops: butterfly over lane bits 3..5 (xor8/permlane16/permlane32)
// Rank-1 fusion: V PC(phi) V^dag = e^{-i phi} I + 2 i sin(phi) v0 v0^dag, v0=V[:,0];
// trailing V^dag, PC(phi4) dropped (ancilla-only, commute with H (x) I).
// No __syncthreads anywhere; LDS is wave-private (x staging + angle tables).

typedef unsigned u32x2_t __attribute__((ext_vector_type(2)));

__device__ __forceinline__ float bperm_f(int addr, float v) {
    return __int_as_float(__builtin_amdgcn_ds_bpermute(addr, __float_as_int(v)));
}

template<int CTRL>
__device__ __forceinline__ float dppf(float v) {
    return __int_as_float(__builtin_amdgcn_update_dpp(
        __float_as_int(v), __float_as_int(v), CTRL, 0xF, 0xF, false));
}

// v[lane ^ (1<<PB)] in lane space, all 64 lanes active. (verified r4-r7)
template<int PB>
__device__ __forceinline__ float xp(float v, int lane) {
    if constexpr (PB == 0) {        // quad_perm [1,0,3,2]
        return dppf<0xB1>(v);
    } else if constexpr (PB == 1) { // quad_perm [2,3,0,1]
        return dppf<0x4E>(v);
    } else if constexpr (PB == 2) { // xor4 = quad_perm[3,2,1,0] o row_half_mirror
        return dppf<0x141>(dppf<0x1B>(v));
    } else if constexpr (PB == 3) { // xor8 = row_ror:8
        return dppf<0x128>(v);
    } else if constexpr (PB == 4) { // xor16
#if __has_builtin(__builtin_amdgcn_permlane16_swap)
        u32x2_t r = __builtin_amdgcn_permlane16_swap(
            (unsigned)__float_as_int(v), (unsigned)__float_as_int(v), false, false);
        return __int_as_float((int)((lane & 16) ? r[0] : r[1]));
#else
        return __int_as_float(__builtin_amdgcn_ds_swizzle(__float_as_int(v), 0x401F));
#endif
    } else {                        // xor32
#if __has_builtin(__builtin_amdgcn_permlane32_swap)
        u32x2_t r = __builtin_amdgcn_permlane32_swap(
            (unsigned)__float_as_int(v), (unsigned)__float_as_int(v), false, false);
        return __int_as_float((int)((lane & 32) ? r[0] : r[1]));
#else
        return bperm_f((lane ^ 32) << 2, v);
#endif
    }
}

// sim14 gate tables (nq=6): type 0=RY, 1=CRX; GA = partner bit (q space),
// GC = CRX control bit (q space). q bit p = 5 - wire.
constexpr int GT[24] = {0,0,0,0,0,0, 1,1,1,1,1,1, 0,0,0,0,0,0, 1,1,1,1,1,1};
constexpr int GA[24] = {5,4,3,2,1,0, 5,0,1,2,3,4, 5,4,3,2,1,0, 1,0,5,4,3,2};
constexpr int GC[24] = {0,0,0,0,0,0, 0,1,2,3,4,5, 0,0,0,0,0,0, 0,5,4,3,2,1};

template<bool ADJ, int GI>
__device__ __forceinline__ void gate_one(float (&sx)[8], float (&sy)[8],
                                         const float2 (&cs)[24], int lane) {
    constexpr int g  = ADJ ? 23 - GI : GI;
    constexpr int pb = GA[g];
    const float c = cs[g].x;
    const float s = ADJ ? -cs[g].y : cs[g].y;
    if constexpr (GT[g] == 0) {                 // ---- RY ----
        if constexpr (pb < 3) {                 // register-pair rotation
            constexpr int m = 1 << pb;
            #pragma unroll
            for (int q0 = 0; q0 < 8; ++q0) {
                if ((q0 & m) == 0) {
                    const int q1 = q0 | m;
                    float t0x = c * sx[q0] - s * sx[q1], t0y = c * sy[q0] - s * sy[q1];
                    float t1x = s * sx[q0] + c * sx[q1], t1y = s * sy[q0] + c * sy[q1];
                    sx[q0] = t0x; sy[q0] = t0y; sx[q1] = t1x; sy[q1] = t1y;
                }
            }
        } else {                                // cross-lane partner
            const float ss = ((lane >> (pb - 3)) & 1) ? s : -s;
            #pragma unroll
            for (int q = 0; q < 8; ++q) {
                const float px = xp<pb - 3>(sx[q], lane);
                const float py = xp<pb - 3>(sy[q], lane);
                sx[q] = c * sx[q] + ss * px;
                sy[q] = c * sy[q] + ss * py;
            }
        }
    } else {                                    // ---- CRX ----
        constexpr int cb = GC[g];
        if constexpr (pb < 3) {
            constexpr int m = 1 << pb;
            if constexpr (cb < 3) {             // ctrl register bit, tgt register bit
                constexpr int cm = 1 << cb;
                #pragma unroll
                for (int q0 = 0; q0 < 8; ++q0) {
                    if ((q0 & m) == 0 && (q0 & cm)) {
                        const int q1 = q0 | m;
                        float nx0 = c * sx[q0] + s * sy[q1], ny0 = c * sy[q0] - s * sx[q1];
                        float nx1 = c * sx[q1] + s * sy[q0], ny1 = c * sy[q1] - s * sx[q0];
                        sx[q0] = nx0; sy[q0] = ny0; sx[q1] = nx1; sy[q1] = ny1;
                    }
                }
            } else {                            // ctrl lane bit, tgt register bit
                const bool  ctrl = (lane >> (cb - 3)) & 1;
                const float ce = ctrl ? c : 1.f, se = ctrl ? s : 0.f;
                float nx[8], ny[8];
                #pragma unroll
                for (int q = 0; q < 8; ++q) {
                    nx[q] = ce * sx[q] + se * sy[q ^ m];
                    ny[q] = ce * sy[q] - se * sx[q ^ m];
                }
                #pragma unroll
                for (int q = 0; q < 8; ++q) { sx[q] = nx[q]; sy[q] = ny[q]; }
            }
        } else {
            if constexpr (cb < 3) {             // ctrl register bit, tgt lane bit
                constexpr int cm = 1 << cb;
                #pragma unroll
                for (int q = 0; q < 8; ++q) {
                    if (q & cm) {
                        const float px = xp<pb - 3>(sx[q], lane);
                        const float py = xp<pb - 3>(sy[q], lane);
                        const float nx = c * sx[q] + s * py;
                        const float ny = c * sy[q] - s * px;
                        sx[q] = nx; sy[q] = ny;
                    }
                }
            } else {                            // ctrl lane bit, tgt lane bit
                const bool  ctrl = (lane >> (cb - 3)) & 1;
                const float ce = ctrl ? c : 1.f, se = ctrl ? s : 0.f;
                #pragma unroll
                for (int q = 0; q < 8; ++q) {
                    const float px = xp<pb - 3>(sx[q], lane);
                    const float py = xp<pb - 3>(sy[q], lane);
                    const float nx = ce * sx[q] + se * py;
                    const float ny = ce * sy[q] - se * px;
                    sx[q] = nx; sy[q] = ny;
                }
            }
        }
    }
}

template<bool ADJ, int GI>
__device__ __forceinline__ void gates_from(float (&sx)[8], float (&sy)[8],
                                           const float2 (&cs)[24], int lane) {
    if constexpr (GI < 24) {
        gate_one<ADJ, GI>(sx, sy, cs, lane);
        gates_from<ADJ, GI + 1>(sx, sy, cs, lane);
    }
}

// k-local expectation for window W; per-lane partial (reduce afterwards).
template<int W>
__device__ __forceinline__ float window_ex(const float (&sx)[8], const float (&sy)[8],
                                           int lane,
                                           const float* __restrict__ Ddiag,
                                           const float* __restrict__ Aoff,
                                           const float* __restrict__ Boff) {
    constexpr int bh = 5 - W, bl = 4 - W;       // window q-bits (bh > bl)
    const float hd0 = 2.f * Ddiag[W * 4 + 1];
    const float hd1 = 2.f * Ddiag[W * 4 + 2];
    const float hd2 = 2.f * Ddiag[W * 4 + 3];
    float ha[6], hb[6];
    #pragma unroll
    for (int j = 0; j < 6; ++j) { ha[j] = Aoff[W * 6 + j]; hb[j] = Boff[W * 6 + j]; }
    bool ok = true;
    if constexpr (bh >= 3) ok = ok && (((lane >> (bh - 3)) & 1) == 0);
    if constexpr (bl >= 3) ok = ok && (((lane >> (bl - 3)) & 1) == 0);
    float ex = 0.f;
    #pragma unroll
    for (int ql = 0; ql < 8; ++ql) {
        // base registers only (window register-bits clear); compile-time folds
        if (!((bh < 3 && ((ql >> bh) & 1)) || (bl < 3 && ((ql >> bl) & 1)))) {
            const float p0x = sx[ql], p0y = sy[ql];
            float p1x, p1y, p2x, p2y, p3x, p3y;
            if constexpr (bl < 3) { p1x = sx[ql | (1 << bl)]; p1y = sy[ql | (1 << bl)]; }
            else { p1x = xp<bl - 3>(sx[ql], lane); p1y = xp<bl - 3>(sy[ql], lane); }
            if constexpr (bh < 3) { p2x = sx[ql | (1 << bh)]; p2y = sy[ql | (1 << bh)]; }
            else { p2x = xp<bh - 3>(sx[ql], lane); p2y = xp<bh - 3>(sy[ql], lane); }
            if constexpr (bh < 3) {             // (implies bl < 3)
                p3x = sx[ql | (1 << bh) | (1 << bl)]; p3y = sy[ql | (1 << bh) | (1 << bl)];
            } else if constexpr (bl < 3) {
                p3x = xp<bh - 3>(sx[ql | (1 << bl)], lane);
                p3y = xp<bh - 3>(sy[ql | (1 << bl)], lane);
            } else {
                p3x = xp<bh - 3>(p1x, lane); p3y = xp<bh - 3>(p1y, lane);
            }
            float val = hd0 * (p0x * p0x + p0y * p0y)
                      + hd1 * (p1x * p1x + p1y * p1y)
                      + hd2 * (p2x * p2x + p2y * p2y);
            val += 2.f * (ha[0] * (p0x * p1x + p0y * p1y) + hb[0] * (p0x * p1y - p0y * p1x));
            val += 2.f * (ha[1] * (p0x * p2x + p0y * p2y) + hb[1] * (p0x * p2y - p0y * p2x));
            val += 2.f * (ha[2] * (p1x * p2x + p1y * p2y) + hb[2] * (p1x * p2y - p1y * p2x));
            val += 2.f * (ha[3] * (p0x * p3x + p0y * p3y) + hb[3] * (p0x * p3y - p0y * p3x));
            val += 2.f * (ha[4] * (p1x * p3x + p1y * p3y) + hb[4] * (p1x * p3y - p1y * p3x));
            val += 2.f * (ha[5] * (p2x * p3x + p2y * p3y) + hb[5] * (p2x * p3y - p2y * p3x));
            ex += ok ? val : 0.f;
        }
    }
    return ex;
}

__device__ __forceinline__ float allred(float v, int lane) {
    v += xp<0>(v, lane); v += xp<1>(v, lane); v += xp<2>(v, lane);
    v += xp<3>(v, lane); v += xp<4>(v, lane); v += xp<5>(v, lane);
    return v;
}

__global__ void __launch_bounds__(64)
qts_kernel(const float* __restrict__ x,      // (B,64,8)
           const float* __restrict__ Wp,     // (24,64)
           const float* __restrict__ bpj,    // (24,)
           const float* __restrict__ prep,   // (3,3,2)
           const float* __restrict__ sig,    // (5,)
           const float* __restrict__ qff,    // (24,)
           const float* __restrict__ Aoff,   // (5,6)
           const float* __restrict__ Boff,   // (5,6)
           const float* __restrict__ Ddiag,  // (5,4)
           const float* __restrict__ Wh,     // (3,5)
           const float* __restrict__ bh,     // (3,)
           float* __restrict__ out)          // (B,3)
{
    __shared__ float  xs[8 * 68];     // x[b] transposed [t][f], stride 68
    __shared__ float2 csA[192];       // cos/sin(ts/2), [t][r]
    __shared__ float2 csQs[24];       // cos/sin(qff/2)

    const int lane = threadIdx.x;     // 0..63; one wave per block
    const int b    = blockIdx.x;

    // ---- stage x (lane owns feature row f=lane: 8 t-values) ----
    {
        const float4 v0_ = ((const float4*)(x + b * 512))[lane * 2];
        const float4 v1_ = ((const float4*)(x + b * 512))[lane * 2 + 1];
        xs[0 * 68 + lane] = v0_.x; xs[1 * 68 + lane] = v0_.y;
        xs[2 * 68 + lane] = v0_.z; xs[3 * 68 + lane] = v0_.w;
        xs[4 * 68 + lane] = v1_.x; xs[5 * 68 + lane] = v1_.y;
        xs[6 * 68 + lane] = v1_.z; xs[7 * 68 + lane] = v1_.w;
    }
    if (lane < 24) {
        float sq, cq; sincosf(0.5f * qff[lane], &sq, &cq);
        csQs[lane] = make_float2(cq, sq);
    }

    // ---- build v0 = V[:,0] redundantly in registers (all lanes) ----
    float vrx[8], vry[8];
    #pragma unroll
    for (int r = 0; r < 8; ++r) { vrx[r] = (r == 0) ? 1.f : 0.f; vry[r] = 0.f; }
    #pragma unroll
    for (int ly = 0; ly < 3; ++ly) {
        #pragma unroll
        for (int qw = 0; qw < 3; ++qw) {
            const int m = 1 << (2 - qw);
            float s0, c0; sincosf(0.5f * prep[(ly * 3 + qw) * 2 + 0], &s0, &c0);
            #pragma unroll
            for (int rr = 0; rr < 4; ++rr) {
                const int lo = rr & (m - 1);
                const int r0 = ((rr & ~(m - 1)) << 1) | lo;
                const int r1 = r0 | m;
                float t0x = c0 * vrx[r0] - s0 * vrx[r1], t0y = c0 * vry[r0] - s0 * vry[r1];
                float t1x = s0 * vrx[r0] + c0 * vrx[r1], t1y = s0 * vry[r0] + c0 * vry[r1];
                vrx[r0] = t0x; vry[r0] = t0y; vrx[r1] = t1x; vry[r1] = t1y;
            }
            float sz, cz; sincosf(0.5f * prep[(ly * 3 + qw) * 2 + 1], &sz, &cz);
            #pragma unroll
            for (int r = 0; r < 8; ++r) {
                const float szz = (r & m) ? sz : -sz;
                float nr = cz * vrx[r] - szz * vry[r];
                float ni = szz * vrx[r] + cz * vry[r];
                vrx[r] = nr; vry[r] = ni;
            }
        }
        float t;
        t = vrx[4]; vrx[4] = vrx[6]; vrx[6] = t;  t = vry[4]; vry[4] = vry[6]; vry[6] = t;
        t = vrx[5]; vrx[5] = vrx[7]; vrx[7] = t;  t = vry[5]; vry[5] = vry[7]; vry[7] = t;
        t = vrx[2]; vrx[2] = vrx[3]; vrx[3] = t;  t = vry[2]; vry[2] = vry[3]; vry[3] = t;
        t = vrx[6]; vrx[6] = vrx[7]; vrx[7] = t;  t = vry[6]; vry[6] = vry[7]; vry[7] = t;
    }
    // v0w = v0[a], a = lane>>3 (static select tree)
    float v0wx, v0wy;
    {
        const bool b3 = lane & 8, b4 = lane & 16, b5 = lane & 32;
        float a0x = b3 ? vrx[1] : vrx[0], a0y = b3 ? vry[1] : vry[0];
        float a1x = b3 ? vrx[3] : vrx[2], a1y = b3 ? vry[3] : vry[2];
        float a2x = b3 ? vrx[5] : vrx[4], a2y = b3 ? vry[5] : vry[4];
        float a3x = b3 ? vrx[7] : vrx[6], a3y = b3 ? vry[7] : vry[6];
        float c0x = b4 ? a1x : a0x, c0y = b4 ? a1y : a0y;
        float c1x = b4 ? a3x : a2x, c1y = b4 ? a3y : a2y;
        v0wx = b5 ? c1x : c0x; v0wy = b5 ? c1y : c0y;
    }

    float sp0, cp0; sincosf(sig[0], &sp0, &cp0);
    float sp1, cp1; sincosf(sig[1], &sp1, &cp1);
    float sp2, cp2; sincosf(sig[2], &sp2, &cp2);
    float sp3, cp3; sincosf(sig[3], &sp3, &cp3);

    // ---- projection: 192 (t,r) dots, 3 per lane ----
    #pragma unroll
    for (int k = 0; k < 3; ++k) {
        const int p = k * 64 + lane;
        const int t = p / 24, r = p - t * 24;
        const float4* wr4 = (const float4*)(Wp + r * 64);
        float z = bpj[r];
        #pragma unroll
        for (int f4 = 0; f4 < 16; ++f4) {
            float4 wv = wr4[f4];
            float4 xv = *(const float4*)(xs + t * 68 + f4 * 4);
            z += wv.x * xv.x + wv.y * xv.y + wv.z * xv.z + wv.w * xv.w;
        }
        const float tv = 1.f / (1.f + expf(-z));
        float sv, cv; sincosf(0.5f * tv, &sv, &cv);
        csA[t * 24 + r] = make_float2(cv, sv);
    }

    // ---- angles into registers ----
    float2 ang[24], angQ[24];
    {
        const int a = lane >> 3;
        #pragma unroll
        for (int g = 0; g < 24; ++g) ang[g] = csA[a * 24 + g];
        #pragma unroll
        for (int g = 0; g < 24; ++g) angQ[g] = csQs[g];
    }

    // ---- state: psi0 = e^{i phi0} v0[a] at q=0 ----
    float sx[8], sy[8];
    {
        const float m0 = ((lane & 7) == 0) ? 1.f : 0.f;
        sx[0] = m0 * (cp0 * v0wx - sp0 * v0wy);
        sy[0] = m0 * (cp0 * v0wy + sp0 * v0wx);
        #pragma unroll
        for (int q = 1; q < 8; ++q) { sx[q] = 0.f; sy[q] = 0.f; }
    }

    // A(phi) = e^{-i phi} I + 2 i sin(phi) v0 v0^dag  (in-register, butterfly over a)
    auto anc_apply = [&](float cp, float sp) {
        float sr[8], si[8];
        #pragma unroll
        for (int q = 0; q < 8; ++q) {
            sr[q] = v0wx * sx[q] + v0wy * sy[q];
            si[q] = v0wx * sy[q] - v0wy * sx[q];
        }
        #pragma unroll
        for (int q = 0; q < 8; ++q) {
            sr[q] += xp<3>(sr[q], lane); si[q] += xp<3>(si[q], lane);
            sr[q] += xp<4>(sr[q], lane); si[q] += xp<4>(si[q], lane);
            sr[q] += xp<5>(sr[q], lane); si[q] += xp<5>(si[q], lane);
        }
        const float ur = -2.f * sp * v0wy, ui = 2.f * sp * v0wx;
        #pragma unroll
        for (int q = 0; q < 8; ++q) {
            const float nx = cp * sx[q] + sp * sy[q] + ur * sr[q] - ui * si[q];
            const float ny = cp * sy[q] - sp * sx[q] + ur * si[q] + ui * sr[q];
            sx[q] = nx; sy[q] = ny;
        }
    };

    gates_from<false, 0>(sx, sy, ang, lane);     // SELECT_0
    anc_apply(cp1, sp1);
    gates_from<true , 0>(sx, sy, ang, lane);     // SELECT_1 (adj)
    anc_apply(cp2, sp2);
    gates_from<false, 0>(sx, sy, ang, lane);     // SELECT_2
    anc_apply(cp3, sp3);
    gates_from<true , 0>(sx, sy, ang, lane);     // SELECT_3 (adj)
    gates_from<false, 0>(sx, sy, angQ, lane);    // QFF unitary

    // ---- expectations ----
    float ex0 = window_ex<0>(sx, sy, lane, Ddiag, Aoff, Boff);
    float ex1 = window_ex<1>(sx, sy, lane, Ddiag, Aoff, Boff);
    float ex2 = window_ex<2>(sx, sy, lane, Ddiag, Aoff, Boff);
    float ex3 = window_ex<3>(sx, sy, lane, Ddiag, Aoff, Boff);
    float ex4 = window_ex<4>(sx, sy, lane, Ddiag, Aoff, Boff);
    ex0 = allred(ex0, lane); ex1 = allred(ex1, lane); ex2 = allred(ex2, lane);
    ex3 = allred(ex3, lane); ex4 = allred(ex4, lane);

    if (lane < 3) {
        float r = bh[lane];
        r += ex0 * Wh[lane * 5 + 0] + ex1 * Wh[lane * 5 + 1] + ex2 * Wh[lane * 5 + 2]
           + ex3 * Wh[lane * 5 + 3] + ex4 * Wh[lane * 5 + 4];
        out[b * 3 + lane] = r;
    }
}

extern "C" void kernel_launch(void* const* d_in, const int* in_sizes, int n_in,
                              void* d_out, int out_size, void* d_ws, size_t ws_size,
                              hipStream_t stream) {
    const int B = in_sizes[0] / (64 * 8);      // 256
    qts_kernel<<<B, 64, 0, stream>>>(
        (const float*)d_in[0], (const float*)d_in[1], (const float*)d_in[2],
        (const float*)d_in[3], (const float*)d_in[4], (const float*)d_in[5],
        (const float*)d_in[6], (const float*)d_in[7], (const float*)d_in[8],
        (const float*)d_in[9], (const float*)d_in[10],
        (float*)d_out);
}

// Round 9
// 14.784 us; speedup vs baseline: 1.9919x; 1.9919x over previous
//
#include <hip/hip_runtime.h>
#include <math.h>

// ModularQTS: B=256, F=64, NT=8, NQ=6 (DQ=64), NA=3 (DA=8), DEG=4, NROTS=24, KLOC=2.
// Round-7 layout (best: 18.6us): one block per batch element, 512 threads = 8 waves;
// wave = ancilla a, lane = main index q, 1 complex amplitude (stx,sty) per thread.
// This round: per-wave-independent setup (no block barrier before SELECT_0),
// lane-space v0 build, fast trig (__sinf/__cosf/__expf).
//
// Algebra (verified r5-r7): psi0 = e^{i phi0}|0>_Q (x) v0;  between SELECTs apply
// A(phi) = e^{-i phi} I + 2 i sin(phi) v0 v0^dag;  trailing V^dag/PC(phi4) dropped.

typedef unsigned u32x2_t __attribute__((ext_vector_type(2)));

__device__ __forceinline__ float bperm_f(int addr, float v) {
    return __int_as_float(__builtin_amdgcn_ds_bpermute(addr, __float_as_int(v)));
}

template<int CTRL>
__device__ __forceinline__ float dppf(float v) {
    return __int_as_float(__builtin_amdgcn_update_dpp(
        __float_as_int(v), __float_as_int(v), CTRL, 0xF, 0xF, false));
}

// v[lane ^ (1<<PB)], all 64 lanes active. (HW-verified r7)
template<int PB>
__device__ __forceinline__ float xp(float v, int lane) {
    if constexpr (PB == 0) {        // quad_perm [1,0,3,2]
        return dppf<0xB1>(v);
    } else if constexpr (PB == 1) { // quad_perm [2,3,0,1]
        return dppf<0x4E>(v);
    } else if constexpr (PB == 2) { // xor4 = quad_perm[3,2,1,0] o row_half_mirror
        return dppf<0x141>(dppf<0x1B>(v));
    } else if constexpr (PB == 3) { // xor8 = row_ror:8
        return dppf<0x128>(v);
    } else if constexpr (PB == 4) { // xor16
#if __has_builtin(__builtin_amdgcn_permlane16_swap)
        u32x2_t r = __builtin_amdgcn_permlane16_swap(
            (unsigned)__float_as_int(v), (unsigned)__float_as_int(v), false, false);
        return __int_as_float((int)((lane & 16) ? r[0] : r[1]));
#else
        return __int_as_float(__builtin_amdgcn_ds_swizzle(__float_as_int(v), 0x401F));
#endif
    } else {                        // xor32
#if __has_builtin(__builtin_amdgcn_permlane32_swap)
        u32x2_t r = __builtin_amdgcn_permlane32_swap(
            (unsigned)__float_as_int(v), (unsigned)__float_as_int(v), false, false);
        return __int_as_float((int)((lane & 32) ? r[0] : r[1]));
#else
        return bperm_f((lane ^ 32) << 2, v);
#endif
    }
}

// sim14 gate tables (nq=6): type 0=RY, 1=CRX; GA = partner bit, GC = CRX control
// bit (q space). q bit p = 5 - wire.  (verified r4-r7)
constexpr int GT[24] = {0,0,0,0,0,0, 1,1,1,1,1,1, 0,0,0,0,0,0, 1,1,1,1,1,1};
constexpr int GA[24] = {5,4,3,2,1,0, 5,0,1,2,3,4, 5,4,3,2,1,0, 1,0,5,4,3,2};
constexpr int GC[24] = {0,0,0,0,0,0, 0,1,2,3,4,5, 0,0,0,0,0,0, 0,5,4,3,2,1};

template<bool ADJ, int GI>
__device__ __forceinline__ void gate_one(float& stx, float& sty,
                                         const float2 (&cs)[24], int lane) {
    constexpr int g  = ADJ ? 23 - GI : GI;
    constexpr int pb = GA[g];
    const float c = cs[g].x;
    const float s = ADJ ? -cs[g].y : cs[g].y;
    const float prx = xp<pb>(stx, lane);
    const float pry = xp<pb>(sty, lane);
    if constexpr (GT[g] == 0) {     // RY
        const float ss = ((lane >> pb) & 1) ? s : -s;
        stx = c * stx + ss * prx;
        sty = c * sty + ss * pry;
    } else {                        // CRX: ctrl=1: c*own + (-i s)*partner
        constexpr int cb = GC[g];
        const bool  ctrl = (lane >> cb) & 1;
        const float ce = ctrl ? c : 1.f;
        const float se = ctrl ? s : 0.f;
        const float nx = ce * stx + se * pry;
        const float ny = ce * sty - se * prx;
        stx = nx; sty = ny;
    }
}

template<bool ADJ, int GI>
__device__ __forceinline__ void gates_from(float& stx, float& sty,
                                           const float2 (&cs)[24], int lane) {
    if constexpr (GI < 24) {
        gate_one<ADJ, GI>(stx, sty, cs, lane);
        gates_from<ADJ, GI + 1>(stx, sty, cs, lane);
    }
}

__global__ void __launch_bounds__(512)
qts_kernel(const float* __restrict__ x,      // (B,64,8)
           const float* __restrict__ Wp,     // (24,64)
           const float* __restrict__ bpj,    // (24,)
           const float* __restrict__ prep,   // (3,3,2)
           const float* __restrict__ sig,    // (5,)
           const float* __restrict__ qff,    // (24,)
           const float* __restrict__ Aoff,   // (5,6)
           const float* __restrict__ Boff,   // (5,6)
           const float* __restrict__ Ddiag,  // (5,4)
           const float* __restrict__ Wh,     // (3,5)
           const float* __restrict__ bh,     // (3,)
           float* __restrict__ out)          // (B,3)
{
    __shared__ float  xsW[8][68];     // per-wave x[:, t=wid]   (272B rows, 16B-aligned)
    __shared__ float2 csW[8][26];     // per-wave SELECT angles (208B rows, 16B-aligned)
    __shared__ float2 csQw[8][26];    // per-wave QFF angles
    __shared__ float2 sl[2][512];     // cross-wave staging [buf][a*64+q]
    __shared__ float  exps_[5];

    const int tid  = threadIdx.x;
    const int lane = tid & 63;
    const int wid  = tid >> 6;        // ancilla index a == timestep t
    const int b    = blockIdx.x;

    // ---- per-wave setup (NO block barriers in this whole phase) ----
    // gather x column t=wid: lane f loads x[b,f,wid]
    const float xg = x[b * 512 + lane * 8 + wid];

    // lane-space v0 = V[:,0] build: lane holds row r = lane&7 (replicated over bits 3-5)
    float vx = ((lane & 7) == 0) ? 1.f : 0.f, vy = 0.f;
    #pragma unroll
    for (int ly = 0; ly < 3; ++ly) {
        #pragma unroll
        for (int qw = 0; qw < 3; ++qw) {
            const int pb = 2 - qw;                    // wire qw <-> bit 2-qw
            const float a0 = 0.5f * prep[(ly * 3 + qw) * 2 + 0];
            const float a1 = 0.5f * prep[(ly * 3 + qw) * 2 + 1];
            const float c0 = __cosf(a0), s0 = __sinf(a0);
            float px, py;
            if (pb == 0)      { px = xp<0>(vx, lane); py = xp<0>(vy, lane); }
            else if (pb == 1) { px = xp<1>(vx, lane); py = xp<1>(vy, lane); }
            else              { px = xp<2>(vx, lane); py = xp<2>(vy, lane); }
            const float sgn = ((lane >> pb) & 1) ? s0 : -s0;   // RY
            vx = c0 * vx + sgn * px;
            vy = c0 * vy + sgn * py;
            const float cz = __cosf(a1), sz = __sinf(a1);      // RZ: e^{-+ i a/2}
            const float szz = ((lane >> pb) & 1) ? sz : -sz;
            const float nx = cz * vx - szz * vy;
            const float ny = szz * vx + cz * vy;
            vx = nx; vy = ny;
        }
        {   // CNOT(0,1): ctrl bit2, tgt bit1 -> rows with bit2 take xor-bit1 partner
            const float px = xp<1>(vx, lane), py = xp<1>(vy, lane);
            const bool c2 = (lane >> 2) & 1;
            vx = c2 ? px : vx; vy = c2 ? py : vy;
        }
        {   // CNOT(1,2): ctrl bit1, tgt bit0
            const float px = xp<0>(vx, lane), py = xp<0>(vy, lane);
            const bool c1 = (lane >> 1) & 1;
            vx = c1 ? px : vx; vy = c1 ? py : vy;
        }
    }
    // wave's v0 element: v0[wid] (held by lane wid; wid < 8)
    const float v0wx = __shfl(vx, wid);
    const float v0wy = __shfl(vy, wid);

    // stage x into per-wave LDS row
    xsW[wid][lane] = xg;

    // QFF angles (per-wave copy), produced on lanes 32..55
    if (lane >= 32 && lane < 56) {
        const int r = lane - 32;
        const float a = 0.5f * qff[r];
        csQw[wid][r] = make_float2(__cosf(a), __sinf(a));
    }
    __builtin_amdgcn_sched_barrier(0);   // xsW writes precede proj reads (same wave)

    // projection for t=wid on lanes 0..23: z = bpj[r] + sum_f x[f,t] Wp[r,f]
    if (lane < 24) {
        const int r = lane;
        const float4* wr4 = (const float4*)(Wp + r * 64);
        float z = bpj[r];
        #pragma unroll
        for (int f4 = 0; f4 < 16; ++f4) {
            const float4 wv = wr4[f4];
            const float4 xv = *(const float4*)(&xsW[wid][f4 * 4]);
            z += wv.x * xv.x + wv.y * xv.y + wv.z * xv.z + wv.w * xv.w;
        }
        const float tv = 1.f / (1.f + __expf(-z));
        csW[wid][r] = make_float2(__cosf(0.5f * tv), __sinf(0.5f * tv));
    }
    __builtin_amdgcn_sched_barrier(0);   // csW/csQw writes precede reads (same wave)

    // SELECT angles into registers
    float2 ang[24];
    #pragma unroll
    for (int g = 0; g < 24; ++g) ang[g] = csW[wid][g];

    // sig phases per-thread (uniform, fast trig)
    const float cp0 = __cosf(sig[0]), sp0 = __sinf(sig[0]);
    const float cp1 = __cosf(sig[1]), sp1 = __sinf(sig[1]);
    const float cp2 = __cosf(sig[2]), sp2 = __sinf(sig[2]);
    const float cp3 = __cosf(sig[3]), sp3 = __sinf(sig[3]);

    // ---- state evolution ----
    float stx = 0.f, sty = 0.f;          // psi0 = e^{i phi0} v0[wid] at q=0
    if (lane == 0) {
        stx = cp0 * v0wx - sp0 * v0wy;
        sty = cp0 * v0wy + sp0 * v0wx;
    }
    int buf = 0;

    // A(phi) = e^{-i phi} I + 2 i sin(phi) v0 v0^dag (ancilla axis, cross-wave)
    auto anc_apply = [&](float cp, float sp) {
        // store conj(v0[a]) * psi  -> cross-wave sum is pure adds
        sl[buf][wid * 64 + lane] = make_float2(v0wx * stx + v0wy * sty,
                                               v0wx * sty - v0wy * stx);
        __syncthreads();
        float sr = 0.f, si = 0.f;
        #pragma unroll
        for (int j = 0; j < 8; ++j) {
            const float2 p = sl[buf][j * 64 + lane];
            sr += p.x; si += p.y;
        }
        const float ur = -2.f * sp * v0wy, ui = 2.f * sp * v0wx;
        const float nx = cp * stx + sp * sty + ur * sr - ui * si;
        const float ny = cp * sty - sp * stx + ur * si + ui * sr;
        stx = nx; sty = ny; buf ^= 1;
    };

    gates_from<false, 0>(stx, sty, ang, lane);   // SELECT_0
    anc_apply(cp1, sp1);
    gates_from<true , 0>(stx, sty, ang, lane);   // SELECT_1 (adj)
    anc_apply(cp2, sp2);
    gates_from<false, 0>(stx, sty, ang, lane);   // SELECT_2
    anc_apply(cp3, sp3);
    gates_from<true , 0>(stx, sty, ang, lane);   // SELECT_3 (adj)

    float2 angQ[24];
    #pragma unroll
    for (int g = 0; g < 24; ++g) angQ[g] = csQw[wid][g];
    gates_from<false, 0>(stx, sty, angQ, lane);  // QFF unitary

    // ---- expectations (verbatim r7, verified) ----
    sl[buf][wid * 64 + lane] = make_float2(stx, sty);
    __syncthreads();

    if (wid < 5) {
        const int w = wid;
        const int bhp = 5 - w, blp = 4 - w;
        const int low_n = 4 - w;
        const float2* sb = sl[buf];
        const float hd0 = 2.f * Ddiag[w * 4 + 1];
        const float hd1 = 2.f * Ddiag[w * 4 + 2];
        const float hd2 = 2.f * Ddiag[w * 4 + 3];
        float ha[6], hb[6];
        #pragma unroll
        for (int j = 0; j < 6; ++j) { ha[j] = Aoff[w * 6 + j]; hb[j] = Boff[w * 6 + j]; }
        float ex = 0.f;
        #pragma unroll
        for (int rep = 0; rep < 2; ++rep) {
            const int mm = lane + rep * 64;
            const int a  = mm & 7;
            const int mq = mm >> 3;
            const int qb = ((mq >> low_n) << (6 - w)) | (mq & ((1 << low_n) - 1));
            const float2 p0 = sb[a * 64 + qb];
            const float2 p1 = sb[a * 64 + (qb | (1 << blp))];
            const float2 p2 = sb[a * 64 + (qb | (1 << bhp))];
            const float2 p3 = sb[a * 64 + (qb | (1 << bhp) | (1 << blp))];
            float val = hd0 * (p0.x * p0.x + p0.y * p0.y)
                      + hd1 * (p1.x * p1.x + p1.y * p1.y)
                      + hd2 * (p2.x * p2.x + p2.y * p2.y);
            val += 2.f * (ha[0] * (p0.x * p1.x + p0.y * p1.y) + hb[0] * (p0.x * p1.y - p0.y * p1.x));
            val += 2.f * (ha[1] * (p0.x * p2.x + p0.y * p2.y) + hb[1] * (p0.x * p2.y - p0.y * p2.x));
            val += 2.f * (ha[2] * (p1.x * p2.x + p1.y * p2.y) + hb[2] * (p1.x * p2.y - p1.y * p2.x));
            val += 2.f * (ha[3] * (p0.x * p3.x + p0.y * p3.y) + hb[3] * (p0.x * p3.y - p0.y * p3.x));
            val += 2.f * (ha[4] * (p1.x * p3.x + p1.y * p3.y) + hb[4] * (p1.x * p3.y - p1.y * p3.x));
            val += 2.f * (ha[5] * (p2.x * p3.x + p2.y * p3.y) + hb[5] * (p2.x * p3.y - p2.y * p3.x));
            ex += val;
        }
        ex += xp<0>(ex, lane); ex += xp<1>(ex, lane); ex += xp<2>(ex, lane);
        ex += xp<3>(ex, lane); ex += xp<4>(ex, lane); ex += xp<5>(ex, lane);
        if (lane == 0) exps_[w] = ex;
    }
    __syncthreads();

    if (tid < 3) {
        float r = bh[tid];
        #pragma unroll
        for (int w = 0; w < 5; ++w) r += exps_[w] * Wh[tid * 5 + w];
        out[b * 3 + tid] = r;
    }
}

extern "C" void kernel_launch(void* const* d_in, const int* in_sizes, int n_in,
                              void* d_out, int out_size, void* d_ws, size_t ws_size,
                              hipStream_t stream) {
    const int B = in_sizes[0] / (64 * 8);      // 256
    qts_kernel<<<B, 512, 0, stream>>>(
        (const float*)d_in[0], (const float*)d_in[1], (const float*)d_in[2],
        (const float*)d_in[3], (const float*)d_in[4], (const float*)d_in[5],
        (const float*)d_in[6], (const float*)d_in[7], (const float*)d_in[8],
        (const float*)d_in[9], (const float*)d_in[10],
        (float*)d_out);
}

// Round 10
// 14.565 us; speedup vs baseline: 2.0218x; 1.0150x over previous
//
#include <hip/hip_runtime.h>
#include <math.h>

// ModularQTS: B=256, F=64, NT=8, NQ=6 (DQ=64), NA=3 (DA=8), DEG=4, NROTS=24, KLOC=2.
// Layout (r7/r9, best): one block per batch element, 512 threads = 8 waves;
// wave = ancilla a (== timestep t), lane = main index q, 1 complex amp/thread.
// r9: per-wave-independent setup, lane-space v0 build, fast trig.
// r10: Wp loads hoisted to kernel entry (latency hides under v0 build);
//      projection split 2 lanes/dot (48 active, 32 FMA deep + DPP combine).
//
// Algebra (verified r5-r9): psi0 = e^{i phi0}|0>_Q (x) v0;  between SELECTs apply
// A(phi) = e^{-i phi} I + 2 i sin(phi) v0 v0^dag;  trailing V^dag/PC(phi4) dropped.

typedef unsigned u32x2_t __attribute__((ext_vector_type(2)));

__device__ __forceinline__ float bperm_f(int addr, float v) {
    return __int_as_float(__builtin_amdgcn_ds_bpermute(addr, __float_as_int(v)));
}

template<int CTRL>
__device__ __forceinline__ float dppf(float v) {
    return __int_as_float(__builtin_amdgcn_update_dpp(
        __float_as_int(v), __float_as_int(v), CTRL, 0xF, 0xF, false));
}

// v[lane ^ (1<<PB)], all 64 lanes active. (HW-verified r7-r9)
template<int PB>
__device__ __forceinline__ float xp(float v, int lane) {
    if constexpr (PB == 0) {        // quad_perm [1,0,3,2]
        return dppf<0xB1>(v);
    } else if constexpr (PB == 1) { // quad_perm [2,3,0,1]
        return dppf<0x4E>(v);
    } else if constexpr (PB == 2) { // xor4 = quad_perm[3,2,1,0] o row_half_mirror
        return dppf<0x141>(dppf<0x1B>(v));
    } else if constexpr (PB == 3) { // xor8 = row_ror:8
        return dppf<0x128>(v);
    } else if constexpr (PB == 4) { // xor16
#if __has_builtin(__builtin_amdgcn_permlane16_swap)
        u32x2_t r = __builtin_amdgcn_permlane16_swap(
            (unsigned)__float_as_int(v), (unsigned)__float_as_int(v), false, false);
        return __int_as_float((int)((lane & 16) ? r[0] : r[1]));
#else
        return __int_as_float(__builtin_amdgcn_ds_swizzle(__float_as_int(v), 0x401F));
#endif
    } else {                        // xor32
#if __has_builtin(__builtin_amdgcn_permlane32_swap)
        u32x2_t r = __builtin_amdgcn_permlane32_swap(
            (unsigned)__float_as_int(v), (unsigned)__float_as_int(v), false, false);
        return __int_as_float((int)((lane & 32) ? r[0] : r[1]));
#else
        return bperm_f((lane ^ 32) << 2, v);
#endif
    }
}

// sim14 gate tables (nq=6): type 0=RY, 1=CRX; GA = partner bit, GC = CRX control
// bit (q space). q bit p = 5 - wire.  (verified r4-r9)
constexpr int GT[24] = {0,0,0,0,0,0, 1,1,1,1,1,1, 0,0,0,0,0,0, 1,1,1,1,1,1};
constexpr int GA[24] = {5,4,3,2,1,0, 5,0,1,2,3,4, 5,4,3,2,1,0, 1,0,5,4,3,2};
constexpr int GC[24] = {0,0,0,0,0,0, 0,1,2,3,4,5, 0,0,0,0,0,0, 0,5,4,3,2,1};

template<bool ADJ, int GI>
__device__ __forceinline__ void gate_one(float& stx, float& sty,
                                         const float2 (&cs)[24], int lane) {
    constexpr int g  = ADJ ? 23 - GI : GI;
    constexpr int pb = GA[g];
    const float c = cs[g].x;
    const float s = ADJ ? -cs[g].y : cs[g].y;
    const float prx = xp<pb>(stx, lane);
    const float pry = xp<pb>(sty, lane);
    if constexpr (GT[g] == 0) {     // RY
        const float ss = ((lane >> pb) & 1) ? s : -s;
        stx = c * stx + ss * prx;
        sty = c * sty + ss * pry;
    } else {                        // CRX: ctrl=1: c*own + (-i s)*partner
        constexpr int cb = GC[g];
        const bool  ctrl = (lane >> cb) & 1;
        const float ce = ctrl ? c : 1.f;
        const float se = ctrl ? s : 0.f;
        const float nx = ce * stx + se * pry;
        const float ny = ce * sty - se * prx;
        stx = nx; sty = ny;
    }
}

template<bool ADJ, int GI>
__device__ __forceinline__ void gates_from(float& stx, float& sty,
                                           const float2 (&cs)[24], int lane) {
    if constexpr (GI < 24) {
        gate_one<ADJ, GI>(stx, sty, cs, lane);
        gates_from<ADJ, GI + 1>(stx, sty, cs, lane);
    }
}

__global__ void __launch_bounds__(512)
qts_kernel(const float* __restrict__ x,      // (B,64,8)
           const float* __restrict__ Wp,     // (24,64)
           const float* __restrict__ bpj,    // (24,)
           const float* __restrict__ prep,   // (3,3,2)
           const float* __restrict__ sig,    // (5,)
           const float* __restrict__ qff,    // (24,)
           const float* __restrict__ Aoff,   // (5,6)
           const float* __restrict__ Boff,   // (5,6)
           const float* __restrict__ Ddiag,  // (5,4)
           const float* __restrict__ Wh,     // (3,5)
           const float* __restrict__ bh,     // (3,)
           float* __restrict__ out)          // (B,3)
{
    __shared__ float  xsW[8][68];     // per-wave x[:, t=wid]
    __shared__ float2 csW[8][26];     // per-wave SELECT angles
    __shared__ float2 csQw[8][26];    // per-wave QFF angles
    __shared__ float2 sl[2][512];     // cross-wave staging [buf][a*64+q]
    __shared__ float  exps_[5];

    const int tid  = threadIdx.x;
    const int lane = tid & 63;
    const int wid  = tid >> 6;        // ancilla index a == timestep t
    const int b    = blockIdx.x;

    // ---- issue global loads FIRST (latency hides under v0 build) ----
    const float xg = x[b * 512 + lane * 8 + wid];          // x[b, f=lane, t=wid]
    // projection operands: 2 lanes per r (half = lane&1 covers 32 features)
    const int pr   = (lane >> 1) < 24 ? (lane >> 1) : 23;  // lanes 48..63 duplicate
    const int half = lane & 1;
    float4 wv[8];
    {
        const float4* wr4 = (const float4*)(Wp + pr * 64 + half * 32);
        #pragma unroll
        for (int f4 = 0; f4 < 8; ++f4) wv[f4] = wr4[f4];
    }
    const float bpjr = bpj[pr];

    // ---- lane-space v0 = V[:,0] build (all lanes; row r = lane&7) ----
    float vx = ((lane & 7) == 0) ? 1.f : 0.f, vy = 0.f;
    #pragma unroll
    for (int ly = 0; ly < 3; ++ly) {
        #pragma unroll
        for (int qw = 0; qw < 3; ++qw) {
            const int pb = 2 - qw;                    // wire qw <-> bit 2-qw
            const float a0 = 0.5f * prep[(ly * 3 + qw) * 2 + 0];
            const float a1 = 0.5f * prep[(ly * 3 + qw) * 2 + 1];
            const float c0 = __cosf(a0), s0 = __sinf(a0);
            float px, py;
            if (pb == 0)      { px = xp<0>(vx, lane); py = xp<0>(vy, lane); }
            else if (pb == 1) { px = xp<1>(vx, lane); py = xp<1>(vy, lane); }
            else              { px = xp<2>(vx, lane); py = xp<2>(vy, lane); }
            const float sgn = ((lane >> pb) & 1) ? s0 : -s0;   // RY
            vx = c0 * vx + sgn * px;
            vy = c0 * vy + sgn * py;
            const float cz = __cosf(a1), sz = __sinf(a1);      // RZ: e^{-+ i a/2}
            const float szz = ((lane >> pb) & 1) ? sz : -sz;
            const float nx = cz * vx - szz * vy;
            const float ny = szz * vx + cz * vy;
            vx = nx; vy = ny;
        }
        {   // CNOT(0,1): ctrl bit2, tgt bit1
            const float px = xp<1>(vx, lane), py = xp<1>(vy, lane);
            const bool c2 = (lane >> 2) & 1;
            vx = c2 ? px : vx; vy = c2 ? py : vy;
        }
        {   // CNOT(1,2): ctrl bit1, tgt bit0
            const float px = xp<0>(vx, lane), py = xp<0>(vy, lane);
            const bool c1 = (lane >> 1) & 1;
            vx = c1 ? px : vx; vy = c1 ? py : vy;
        }
    }
    const float v0wx = __shfl(vx, wid);               // v0[wid]
    const float v0wy = __shfl(vy, wid);

    // stage x into per-wave LDS row
    xsW[wid][lane] = xg;

    // QFF angles (per-wave copy), lanes 32..55
    if (lane >= 32 && lane < 56) {
        const int r = lane - 32;
        const float a = 0.5f * qff[r];
        csQw[wid][r] = make_float2(__cosf(a), __sinf(a));
    }
    __builtin_amdgcn_sched_barrier(0);   // xsW writes precede proj reads (same wave)

    // ---- projection: z = bpj[r] + sum_f x[f,t] Wp[r,f]; 2 lanes per r ----
    {
        float z = half ? 0.f : bpjr;
        #pragma unroll
        for (int f4 = 0; f4 < 8; ++f4) {
            const float4 xv = *(const float4*)(&xsW[wid][half * 32 + f4 * 4]);
            z += wv[f4].x * xv.x + wv[f4].y * xv.y + wv[f4].z * xv.z + wv[f4].w * xv.w;
        }
        z += xp<0>(z, lane);                          // pair combine (xor1)
        if (lane < 48 && half == 0) {
            const float tv = 1.f / (1.f + __expf(-z));
            csW[wid][lane >> 1] = make_float2(__cosf(0.5f * tv), __sinf(0.5f * tv));
        }
    }
    __builtin_amdgcn_sched_barrier(0);   // csW/csQw writes precede reads (same wave)

    // SELECT angles into registers
    float2 ang[24];
    #pragma unroll
    for (int g = 0; g < 24; ++g) ang[g] = csW[wid][g];

    const float cp0 = __cosf(sig[0]), sp0 = __sinf(sig[0]);
    const float cp1 = __cosf(sig[1]), sp1 = __sinf(sig[1]);
    const float cp2 = __cosf(sig[2]), sp2 = __sinf(sig[2]);
    const float cp3 = __cosf(sig[3]), sp3 = __sinf(sig[3]);

    // ---- state evolution ----
    float stx = 0.f, sty = 0.f;          // psi0 = e^{i phi0} v0[wid] at q=0
    if (lane == 0) {
        stx = cp0 * v0wx - sp0 * v0wy;
        sty = cp0 * v0wy + sp0 * v0wx;
    }
    int buf = 0;

    // A(phi) = e^{-i phi} I + 2 i sin(phi) v0 v0^dag (ancilla axis, cross-wave)
    auto anc_apply = [&](float cp, float sp) {
        sl[buf][wid * 64 + lane] = make_float2(v0wx * stx + v0wy * sty,
                                               v0wx * sty - v0wy * stx);
        __syncthreads();
        float sr = 0.f, si = 0.f;
        #pragma unroll
        for (int j = 0; j < 8; ++j) {
            const float2 p = sl[buf][j * 64 + lane];
            sr += p.x; si += p.y;
        }
        const float ur = -2.f * sp * v0wy, ui = 2.f * sp * v0wx;
        const float nx = cp * stx + sp * sty + ur * sr - ui * si;
        const float ny = cp * sty - sp * stx + ur * si + ui * sr;
        stx = nx; sty = ny; buf ^= 1;
    };

    gates_from<false, 0>(stx, sty, ang, lane);   // SELECT_0
    anc_apply(cp1, sp1);
    gates_from<true , 0>(stx, sty, ang, lane);   // SELECT_1 (adj)
    anc_apply(cp2, sp2);
    gates_from<false, 0>(stx, sty, ang, lane);   // SELECT_2
    anc_apply(cp3, sp3);
    gates_from<true , 0>(stx, sty, ang, lane);   // SELECT_3 (adj)

    float2 angQ[24];
    #pragma unroll
    for (int g = 0; g < 24; ++g) angQ[g] = csQw[wid][g];
    gates_from<false, 0>(stx, sty, angQ, lane);  // QFF unitary

    // ---- expectations (verified r7/r9) ----
    sl[buf][wid * 64 + lane] = make_float2(stx, sty);
    __syncthreads();

    if (wid < 5) {
        const int w = wid;
        const int bhp = 5 - w, blp = 4 - w;
        const int low_n = 4 - w;
        const float2* sb = sl[buf];
        const float hd0 = 2.f * Ddiag[w * 4 + 1];
        const float hd1 = 2.f * Ddiag[w * 4 + 2];
        const float hd2 = 2.f * Ddiag[w * 4 + 3];
        float ha[6], hb[6];
        #pragma unroll
        for (int j = 0; j < 6; ++j) { ha[j] = Aoff[w * 6 + j]; hb[j] = Boff[w * 6 + j]; }
        float ex = 0.f;
        #pragma unroll
        for (int rep = 0; rep < 2; ++rep) {
            const int mm = lane + rep * 64;
            const int a  = mm & 7;
            const int mq = mm >> 3;
            const int qb = ((mq >> low_n) << (6 - w)) | (mq & ((1 << low_n) - 1));
            const float2 p0 = sb[a * 64 + qb];
            const float2 p1 = sb[a * 64 + (qb | (1 << blp))];
            const float2 p2 = sb[a * 64 + (qb | (1 << bhp))];
            const float2 p3 = sb[a * 64 + (qb | (1 << bhp) | (1 << blp))];
            float val = hd0 * (p0.x * p0.x + p0.y * p0.y)
                      + hd1 * (p1.x * p1.x + p1.y * p1.y)
                      + hd2 * (p2.x * p2.x + p2.y * p2.y);
            val += 2.f * (ha[0] * (p0.x * p1.x + p0.y * p1.y) + hb[0] * (p0.x * p1.y - p0.y * p1.x));
            val += 2.f * (ha[1] * (p0.x * p2.x + p0.y * p2.y) + hb[1] * (p0.x * p2.y - p0.y * p2.x));
            val += 2.f * (ha[2] * (p1.x * p2.x + p1.y * p2.y) + hb[2] * (p1.x * p2.y - p1.y * p2.x));
            val += 2.f * (ha[3] * (p0.x * p3.x + p0.y * p3.y) + hb[3] * (p0.x * p3.y - p0.y * p3.x));
            val += 2.f * (ha[4] * (p1.x * p3.x + p1.y * p3.y) + hb[4] * (p1.x * p3.y - p1.y * p3.x));
            val += 2.f * (ha[5] * (p2.x * p3.x + p2.y * p3.y) + hb[5] * (p2.x * p3.y - p2.y * p3.x));
            ex += val;
        }
        ex += xp<0>(ex, lane); ex += xp<1>(ex, lane); ex += xp<2>(ex, lane);
        ex += xp<3>(ex, lane); ex += xp<4>(ex, lane); ex += xp<5>(ex, lane);
        if (lane == 0) exps_[w] = ex;
    }
    __syncthreads();

    if (tid < 3) {
        float r = bh[tid];
        #pragma unroll
        for (int w = 0; w < 5; ++w) r += exps_[w] * Wh[tid * 5 + w];
        out[b * 3 + tid] = r;
    }
}

extern "C" void kernel_launch(void* const* d_in, const int* in_sizes, int n_in,
                              void* d_out, int out_size, void* d_ws, size_t ws_size,
                              hipStream_t stream) {
    const int B = in_sizes[0] / (64 * 8);      // 256
    qts_kernel<<<B, 512, 0, stream>>>(
        (const float*)d_in[0], (const float*)d_in[1], (const float*)d_in[2],
        (const float*)d_in[3], (const float*)d_in[4], (const float*)d_in[5],
        (const float*)d_in[6], (const float*)d_in[7], (const float*)d_in[8],
        (const float*)d_in[9], (const float*)d_in[10],
        (float*)d_out);
}